// Round 16
// baseline (113.459 us; speedup 1.0000x reference)
//
#include <hip/hip_runtime.h>

// MinEuclideanDistBlock: x(32,8,4096) f32, shapelets(8,128,64) f32 -> out(32,1,128) f32
// out[b,k] = min_w sum_c sqrt( xnorm[b,c,w] + snorm[c,k] - 2*sum_s x[b,c,w+s]*h[c,k,s] )
//
// R17 -> R18 (post-mortem: second consecutive win 54.4->52.2us; VGPR exactly 84,
// occ 24% as modeled. ILP and TLP both work but asymptote at ~4% each. Next removable
// cost: the in-loop x-staging chain (6 loads + ~30 VALU f2bf + 3 ds_writes per thread
// per c-iter ~= 7% of issue + cross-phase dependency edges anchoring barrier 2):
//  - ALL-channel Xr staged once in the prologue (25.6 KB single-buffered; R6 proved
//    this staging works - its failure was global-B reads, which stay DMA'd here).
//    Main loop is now pure {stage_half DMA, ds_read, MFMA, sqrt} phases.
//  - LDS 31.2 -> 49.6 KB: still 3 WGs/CU by LDS = exactly the VGPR-allowed residency
//    (no cap change). Frees ~9 VGPRs of demand (xf, x_lds, temps) as scheduler slack
//    under the 85 budget.
//  - Inner loop, DMA pipeline, barriers, arithmetic order: byte-identical to R17
//    -> same numerics.
//  - Tripwires: VGPR > 85 or WRITE_SIZE >> 2MB -> revert staging split.

typedef short short8 __attribute__((ext_vector_type(8)));
typedef float f32x4 __attribute__((ext_vector_type(4)));

constexpr int Bn = 32, Cn = 8, Ln = 4096, Kn = 128, Sn = 64;
constexpr int Wn = Ln - Sn + 1;          // 4033
constexpr int WT = 128;                  // windows per block
constexpr int NWT = (Wn + WT - 1) / WT;  // 32
constexpr int BDIM = 256;

typedef const __attribute__((address_space(1))) unsigned int gas_u32;
typedef __attribute__((address_space(3))) unsigned int las_u32;

__device__ __forceinline__ unsigned int f2bf(float f) {
  unsigned int u = __float_as_uint(f);
  u += 0x7FFFu + ((u >> 16) & 1u);       // round-to-nearest-even
  return u >> 16;
}

// ws layout: [0, 128KB): ushort hbf[C][K][S] = bf16(-2*h), byte-swizzled ^((k&7)<<4)
//            [128KB, +4KB): float snorm[C][K]
__global__ void prep_kernel(const float* __restrict__ sh,
                            unsigned int* __restrict__ out,
                            unsigned short* __restrict__ hbf,
                            float* __restrict__ snorm) {
  int gid = blockIdx.x * blockDim.x + threadIdx.x;  // 0..4095
  out[gid] = 0x7F7FFFFFu;                           // FLT_MAX bits (Bn*Kn == 4096)
  if (gid < Cn * Kn) {
    const float4* row = (const float4*)(sh + (size_t)gid * Sn);
    char* rowb = (char*)hbf + (size_t)gid * (Sn * 2);   // 128B row
    const unsigned int sw = (gid & 7u) << 4;            // (k&7)<<4 byte swizzle
    float a = 0.f;
    #pragma unroll
    for (int i = 0; i < 16; ++i) {
      float4 v = row[i];
      a += v.x * v.x + v.y * v.y + v.z * v.z + v.w * v.w;
      unsigned int p0 = f2bf(-2.f * v.x) | (f2bf(-2.f * v.y) << 16);
      unsigned int p1 = f2bf(-2.f * v.z) | (f2bf(-2.f * v.w) << 16);
      *(uint2*)(rowb + ((8u * i) ^ sw)) = make_uint2(p0, p1);  // stays 8B-aligned
    }
    snorm[gid] = a;
  }
}

__launch_bounds__(BDIM, 3)
__global__ void med_kernel(const float* __restrict__ x,
                           const unsigned short* __restrict__ hbf,
                           const float* __restrict__ snorm,
                           unsigned int* __restrict__ out) {
  constexpr int XRS = 200;  // Xr row stride (elems); 400B, 16B-aligned rows
  __shared__ __align__(16) unsigned short Xr[Cn][8 * XRS];  // 8 x 3.2KB = 25.6KB
  __shared__ __align__(16) unsigned short Bs[2][64 * Sn];   // 2 x 8KB (K-half each)
  __shared__ __align__(16) float xnormC[Cn * WT];           // 4KB
  __shared__ __align__(16) float snormC[Cn * Kn];           // 4KB

  const int tid  = threadIdx.x;
  const int b    = blockIdx.y;
  const int w0   = blockIdx.x * WT;
  const int lane = tid & 63;
  const int wv   = tid >> 6;     // wave 0..3
  const int quad = lane >> 4;    // 0..3
  const int n16  = lane & 15;
  const int wbase = wv * 32;     // this wave's window offset in tile

  const float* xb = x + (size_t)b * Cn * Ln;

  // ---- B staging: linear global->LDS DMA of one pre-swizzled 8KB K-half ----
  auto stage_half = [&](int bufi, int c, int p) {
    const char* src = (const char*)hbf + ((size_t)c * Kn + p * 64) * (Sn * 2);
    char* dst = (char*)&Bs[bufi][0];
    #pragma unroll
    for (int rep = 0; rep < 2; ++rep) {
      int q16 = (tid + rep * BDIM) * 16;   // lane-linear 16B chunks, 0..8191
      __builtin_amdgcn_global_load_lds((gas_u32*)(src + q16), (las_u32*)(dst + q16),
                                       16, 0, 0);
    }
  };

  // snorm: one float4 per thread from prep output
  ((float4*)snormC)[tid] = ((const float4*)snorm)[tid];

  // ---- prologue: stage (c=0, pass=0) DMA first (overlaps all prologue compute) ----
  stage_half(0, 0, 0);

  // ---- prologue: stage ALL channels' shifted bf16 x rows (once, single-buffered) ----
  for (int c = 0; c < Cn; ++c) {
    const float* xc = xb + (size_t)c * Ln;
    #pragma unroll
    for (int rep = 0; rep < 3; ++rep) {
      int pid = tid + rep * BDIM;       // 0..767
      int r = pid / 96;
      int p = pid - r * 96;             // pair index 0..95 -> elems 2p,2p+1
      int i0 = w0 + r + 2 * p;
      float f0 = (i0 < Ln) ? xc[i0] : 0.f;
      float f1 = (i0 + 1 < Ln) ? xc[i0 + 1] : 0.f;
      *(unsigned int*)(&Xr[c][r * XRS + 2 * p]) = f2bf(f0) | (f2bf(f1) << 16);
    }
  }

  // xnorm: 256 threads = 8c x 32 groups, 4 windows each (rolling update), fp32-exact
  {
    int c  = tid >> 5;
    int m0 = (tid & 31) * 4;
    const float* xc = xb + c * Ln;
    auto xq = [&](int i) -> float {
      float v = (i < Ln) ? xc[i] : 0.f;
      return v * v;
    };
    float s0 = 0.f;
    for (int s = 0; s < Sn; ++s) s0 += xq(w0 + m0 + s);
    float s1 = s0 - xq(w0 + m0 + 0) + xq(w0 + m0 + 64);
    float s2 = s1 - xq(w0 + m0 + 1) + xq(w0 + m0 + 65);
    float s3 = s2 - xq(w0 + m0 + 2) + xq(w0 + m0 + 66);
    xnormC[c * WT + m0 + 0] = s0;
    xnormC[c * WT + m0 + 1] = s1;
    xnormC[c * WT + m0 + 2] = s2;
    xnormC[c * WT + m0 + 3] = s3;
  }
  __syncthreads();  // drains prologue DMA (implicit vmcnt(0)) + publishes Xr/norms

  float dist[2][8][4] = {};  // [mtile][ntile2][reg] summed distance over c

  for (int c = 0; c < Cn; ++c) {
    // ================= phase 0: compute K-half 0, DMA K-half 1 =================
    stage_half(1, c, 1);            // async DMA pass-1 half into Bs[1]

    // A fragments: lane m = n16, k = quad*8+j (+ks*32); one aligned b128 each
    short8 af[2][2];
    #pragma unroll
    for (int mt = 0; mt < 2; ++mt)
      #pragma unroll
      for (int ks = 0; ks < 2; ++ks) {
        int i = wbase + mt * 16 + n16 + ks * 32 + quad * 8;
        af[mt][ks] = *(const short8*)(&Xr[c][(i & 7) * XRS + (i >> 3) * 8]);
      }

    #pragma unroll
    for (int pass = 0; pass < 2; ++pass) {
      const char* bsb = (const char*)&Bs[pass][0];
      // nt in PAIRS: 4 independent acc units, 8 MFMA grouped by k-slice,
      // 16 independent sqrts per half-pass.
      #pragma unroll
      for (int hp = 0; hp < 2; ++hp) {
        const int ntA = hp * 2, ntB = ntA + 1;
        const int kshA = ntA * 16 + n16;            // k-row within half: 0..63
        const float snA = snormC[c * Kn + pass * 64 + kshA];
        const float snB = snormC[c * Kn + pass * 64 + kshA + 16];
        const int boffA = (kshA * 128 + quad * 16) ^ ((kshA & 7) << 4);
        const int boffB = boffA + 2048;             // (ksh+16)&7 == ksh&7

        // xn re-read per half-pass (dead after init: caps live regs)
        float4 xn0 = *(const float4*)(&xnormC[c * WT + wbase + quad * 4]);
        float4 xn1 = *(const float4*)(&xnormC[c * WT + wbase + 16 + quad * 4]);

        f32x4 a00, a01, a10, a11;                   // acc[mt][A/B]
        #pragma unroll
        for (int rg = 0; rg < 4; ++rg) {
          a00[rg] = xn0[rg] + snA;
          a01[rg] = xn0[rg] + snB;
          a10[rg] = xn1[rg] + snA;
          a11[rg] = xn1[rg] + snB;
        }

        // k-slice 0: two B frags, 4 independent MFMA
        {
          short8 bA0 = *(const short8*)(bsb + boffA);
          short8 bB0 = *(const short8*)(bsb + boffB);
          a00 = __builtin_amdgcn_mfma_f32_16x16x32_bf16(af[0][0], bA0, a00, 0, 0, 0);
          a01 = __builtin_amdgcn_mfma_f32_16x16x32_bf16(af[0][0], bB0, a01, 0, 0, 0);
          a10 = __builtin_amdgcn_mfma_f32_16x16x32_bf16(af[1][0], bA0, a10, 0, 0, 0);
          a11 = __builtin_amdgcn_mfma_f32_16x16x32_bf16(af[1][0], bB0, a11, 0, 0, 0);
        }
        // k-slice 1: two more B frags, 4 independent MFMA
        {
          short8 bA1 = *(const short8*)(bsb + (boffA ^ 64));  // swizzle-safe +64B
          short8 bB1 = *(const short8*)(bsb + (boffB ^ 64));
          a00 = __builtin_amdgcn_mfma_f32_16x16x32_bf16(af[0][1], bA1, a00, 0, 0, 0);
          a01 = __builtin_amdgcn_mfma_f32_16x16x32_bf16(af[0][1], bB1, a01, 0, 0, 0);
          a10 = __builtin_amdgcn_mfma_f32_16x16x32_bf16(af[1][1], bA1, a10, 0, 0, 0);
          a11 = __builtin_amdgcn_mfma_f32_16x16x32_bf16(af[1][1], bB1, a11, 0, 0, 0);
        }

        // 16 independent sqrts, then accumulate
        #pragma unroll
        for (int rg = 0; rg < 4; ++rg) {
          dist[0][pass * 4 + ntA][rg] += __builtin_amdgcn_sqrtf(a00[rg]);
          dist[0][pass * 4 + ntB][rg] += __builtin_amdgcn_sqrtf(a01[rg]);
          dist[1][pass * 4 + ntA][rg] += __builtin_amdgcn_sqrtf(a10[rg]);
          dist[1][pass * 4 + ntB][rg] += __builtin_amdgcn_sqrtf(a11[rg]);
        }
      }

      if (pass == 0) {
        // barrier 1: publishes Bs[1] (DMA issued a full phase ago); Bs[0] now dead
        __syncthreads();
        // ============ phase 1: compute K-half 1, DMA next c's K-half 0 ============
        if (c + 1 < Cn) stage_half(0, c + 1, 0);
      }
    }

    __syncthreads();  // barrier 2: Bs[1] reads done before next c's overwrite;
                      // drains next-c K-half-0 DMA (1-phase cover)
  }

  // ---- min over windows, then global combine ----
  const int wql = w0 + wbase + quad * 4;
  #pragma unroll
  for (int nt2 = 0; nt2 < 8; ++nt2) {
    float v = 3.4e38f;
    #pragma unroll
    for (int mt = 0; mt < 2; ++mt)
      #pragma unroll
      for (int rg = 0; rg < 4; ++rg) {
        int wg = wql + mt * 16 + rg;
        float d = (wg < Wn) ? dist[mt][nt2][rg] : 3.4e38f;
        v = fminf(v, d);
      }
    v = fminf(v, __shfl_xor(v, 16, 64));
    v = fminf(v, __shfl_xor(v, 32, 64));
    if (lane < 16)
      atomicMin(&out[b * Kn + nt2 * 16 + n16], __float_as_uint(v));
  }
}

extern "C" void kernel_launch(void* const* d_in, const int* in_sizes, int n_in,
                              void* d_out, int out_size, void* d_ws, size_t ws_size,
                              hipStream_t stream) {
  const float* x  = (const float*)d_in[0];
  const float* sh = (const float*)d_in[1];
  unsigned int* out = (unsigned int*)d_out;
  unsigned short* hbf = (unsigned short*)d_ws;                      // 128 KB
  float* snorm = (float*)((char*)d_ws + (size_t)Cn * Kn * Sn * 2);  // +4 KB
  hipLaunchKernelGGL(prep_kernel, dim3(16), dim3(256), 0, stream, sh, out, hbf, snorm);
  hipLaunchKernelGGL(med_kernel, dim3(NWT, Bn), dim3(BDIM), 0, stream, x, hbf, snorm, out);
}

// Round 17
// 107.182 us; speedup vs baseline: 1.0586x; 1.0586x over previous
//
#include <hip/hip_runtime.h>

// MinEuclideanDistBlock: x(32,8,4096) f32, shapelets(8,128,64) f32 -> out(32,1,128) f32
// out[b,k] = min_w sum_c sqrt( xnorm[b,c,w] + snorm[c,k] - 2*sum_s x[b,c,w+s]*h[c,k,s] )
//
// R18 -> R19 (post-mortem: removing in-loop x-staging REGRESSED 52->70us; VALUBusy
// 37->26% - the staging chain was FILLING stall slots, not creating them. Revert to
// R17 base. Cycle model: LDS-issue floor ~21us, VALU ~12us, measured 52 -> gap is
// barrier-edge latency. Identified waste: barrier 1's vmcnt(0) drains the 6 x-loads
// issued in phase 0 that aren't needed until write_x a full pass later):
//  - load_x(c+1) moved from phase 0 to phase 1 (after barrier 1's stage_half):
//    barrier 1 now drains only the 2 needed Bs[1] DMAs; x-loads get pass-1 to land
//    before write_x. Zero-asm counted-vmcnt equivalent.
//  - snorm transposed in LDS (snT[c][j][nt8]): per-hp 2x ds_read_b32 (stride-16)
//    -> 1x ds_read_b64 of adjacent floats. 8 b32 -> 4 b64 per c-iter, +0 regs.
//  - Inner loop, DMA pipeline, barriers, arithmetic order: identical to R17
//    -> same numerics (absmax 0.5).
//  - Tripwires: VGPR > 85 or WRITE_SIZE >> 2MB -> revert. Gain < 2% -> declare
//    structural floor next round.

typedef short short8 __attribute__((ext_vector_type(8)));
typedef float f32x4 __attribute__((ext_vector_type(4)));
typedef float f32x2 __attribute__((ext_vector_type(2)));

constexpr int Bn = 32, Cn = 8, Ln = 4096, Kn = 128, Sn = 64;
constexpr int Wn = Ln - Sn + 1;          // 4033
constexpr int WT = 128;                  // windows per block
constexpr int NWT = (Wn + WT - 1) / WT;  // 32
constexpr int BDIM = 256;

typedef const __attribute__((address_space(1))) unsigned int gas_u32;
typedef __attribute__((address_space(3))) unsigned int las_u32;

__device__ __forceinline__ unsigned int f2bf(float f) {
  unsigned int u = __float_as_uint(f);
  u += 0x7FFFu + ((u >> 16) & 1u);       // round-to-nearest-even
  return u >> 16;
}

// ws layout: [0, 128KB): ushort hbf[C][K][S] = bf16(-2*h), byte-swizzled ^((k&7)<<4)
//            [128KB, +4KB): float snorm[C][K]
__global__ void prep_kernel(const float* __restrict__ sh,
                            unsigned int* __restrict__ out,
                            unsigned short* __restrict__ hbf,
                            float* __restrict__ snorm) {
  int gid = blockIdx.x * blockDim.x + threadIdx.x;  // 0..4095
  out[gid] = 0x7F7FFFFFu;                           // FLT_MAX bits (Bn*Kn == 4096)
  if (gid < Cn * Kn) {
    const float4* row = (const float4*)(sh + (size_t)gid * Sn);
    char* rowb = (char*)hbf + (size_t)gid * (Sn * 2);   // 128B row
    const unsigned int sw = (gid & 7u) << 4;            // (k&7)<<4 byte swizzle
    float a = 0.f;
    #pragma unroll
    for (int i = 0; i < 16; ++i) {
      float4 v = row[i];
      a += v.x * v.x + v.y * v.y + v.z * v.z + v.w * v.w;
      unsigned int p0 = f2bf(-2.f * v.x) | (f2bf(-2.f * v.y) << 16);
      unsigned int p1 = f2bf(-2.f * v.z) | (f2bf(-2.f * v.w) << 16);
      *(uint2*)(rowb + ((8u * i) ^ sw)) = make_uint2(p0, p1);  // stays 8B-aligned
    }
    snorm[gid] = a;
  }
}

__launch_bounds__(BDIM, 3)
__global__ void med_kernel(const float* __restrict__ x,
                           const unsigned short* __restrict__ hbf,
                           const float* __restrict__ snorm,
                           unsigned int* __restrict__ out) {
  constexpr int XRS = 200;  // Xr row stride (elems); 400B, 16B-aligned rows
  __shared__ __align__(16) unsigned short Xr[2][8 * XRS];   // 2 x 3.2KB
  __shared__ __align__(16) unsigned short Bs[2][64 * Sn];   // 2 x 8KB (K-half each)
  __shared__ __align__(16) float xnormC[Cn * WT];           // 4KB
  __shared__ __align__(16) float snT[Cn * Kn];              // 4KB, [c][j=n16][nt8]

  const int tid  = threadIdx.x;
  const int b    = blockIdx.y;
  const int w0   = blockIdx.x * WT;
  const int lane = tid & 63;
  const int wv   = tid >> 6;     // wave 0..3
  const int quad = lane >> 4;    // 0..3
  const int n16  = lane & 15;
  const int wbase = wv * 32;     // this wave's window offset in tile

  const float* xb = x + (size_t)b * Cn * Ln;

  // ---- B staging: linear global->LDS DMA of one pre-swizzled 8KB K-half ----
  auto stage_half = [&](int bufi, int c, int p) {
    const char* src = (const char*)hbf + ((size_t)c * Kn + p * 64) * (Sn * 2);
    char* dst = (char*)&Bs[bufi][0];
    #pragma unroll
    for (int rep = 0; rep < 2; ++rep) {
      int q16 = (tid + rep * BDIM) * 16;   // lane-linear 16B chunks, 0..8191
      __builtin_amdgcn_global_load_lds((gas_u32*)(src + q16), (las_u32*)(dst + q16),
                                       16, 0, 0);
    }
  };

  // ---- X staging: LDS offsets hoisted; global idx recomputed ----
  int x_lds[3];
  #pragma unroll
  for (int rep = 0; rep < 3; ++rep) {
    int pid = tid + rep * BDIM;       // 0..767
    int r = pid / 96;
    int p = pid - r * 96;             // pair index 0..95 -> elems 2p,2p+1
    x_lds[rep] = r * XRS + 2 * p;
  }
  float xf[3][2];
  auto load_x = [&](int c) {
    const float* xc = xb + (size_t)c * Ln;
    #pragma unroll
    for (int rep = 0; rep < 3; ++rep) {
      int pid = tid + rep * BDIM;
      int r = pid / 96;
      int p = pid - r * 96;
      int i0 = w0 + r + 2 * p;
      xf[rep][0] = (i0 < Ln) ? xc[i0] : 0.f;
      xf[rep][1] = (i0 + 1 < Ln) ? xc[i0 + 1] : 0.f;
    }
  };
  auto write_x = [&](int bufi) {
    #pragma unroll
    for (int rep = 0; rep < 3; ++rep)
      *(unsigned int*)(&Xr[bufi][x_lds[rep]]) =
          f2bf(xf[rep][0]) | (f2bf(xf[rep][1]) << 16);
  };

  // snorm, TRANSPOSED: snT[c*128 + j*8 + nt8] = snorm[c*128 + nt8*16 + j]
  #pragma unroll
  for (int rep = 0; rep < 4; ++rep) {
    int idx = tid * 4 + rep;          // 0..1023
    int c8 = idx >> 7, r = idx & 127;
    int j = r >> 3, nt8 = r & 7;
    snT[idx] = snorm[c8 * 128 + nt8 * 16 + j];
  }

  // ---- prologue: stage (c=0, pass=0) into Bs[0] (DMA overlaps xnorm compute) ----
  stage_half(0, 0, 0);
  load_x(0);

  // xnorm: 256 threads = 8c x 32 groups, 4 windows each (rolling update), fp32-exact
  {
    int c  = tid >> 5;
    int m0 = (tid & 31) * 4;
    const float* xc = xb + c * Ln;
    auto xq = [&](int i) -> float {
      float v = (i < Ln) ? xc[i] : 0.f;
      return v * v;
    };
    float s0 = 0.f;
    for (int s = 0; s < Sn; ++s) s0 += xq(w0 + m0 + s);
    float s1 = s0 - xq(w0 + m0 + 0) + xq(w0 + m0 + 64);
    float s2 = s1 - xq(w0 + m0 + 1) + xq(w0 + m0 + 65);
    float s3 = s2 - xq(w0 + m0 + 2) + xq(w0 + m0 + 66);
    xnormC[c * WT + m0 + 0] = s0;
    xnormC[c * WT + m0 + 1] = s1;
    xnormC[c * WT + m0 + 2] = s2;
    xnormC[c * WT + m0 + 3] = s3;
  }
  write_x(0);
  __syncthreads();  // drains prologue DMA (implicit vmcnt(0)) + covers norm writes

  float dist[2][8][4] = {};  // [mtile][ntile2][reg] summed distance over c

  for (int c = 0; c < Cn; ++c) {
    const int xbuf = c & 1;

    // ================= phase 0: compute K-half 0, DMA K-half 1 =================
    stage_half(1, c, 1);            // async DMA pass-1 half into Bs[1]
    // (x loads for c+1 now issued in phase 1 -> barrier 1 drains ONLY the B DMAs)

    // A fragments: lane m = n16, k = quad*8+j (+ks*32); one aligned b128 each
    short8 af[2][2];
    #pragma unroll
    for (int mt = 0; mt < 2; ++mt)
      #pragma unroll
      for (int ks = 0; ks < 2; ++ks) {
        int i = wbase + mt * 16 + n16 + ks * 32 + quad * 8;
        af[mt][ks] = *(const short8*)(&Xr[xbuf][(i & 7) * XRS + (i >> 3) * 8]);
      }

    #pragma unroll
    for (int pass = 0; pass < 2; ++pass) {
      const char* bsb = (const char*)&Bs[pass][0];
      // nt in PAIRS: 4 independent acc units, 8 MFMA grouped by k-slice,
      // 16 independent sqrts per half-pass.
      #pragma unroll
      for (int hp = 0; hp < 2; ++hp) {
        const int ntA = hp * 2;
        const int kshA = ntA * 16 + n16;            // k-row within half: 0..63
        // transposed snorm: both sn values in ONE aligned b64
        f32x2 snp = *(const f32x2*)(&snT[c * Kn + n16 * 8 + pass * 4 + ntA]);
        const float snA = snp[0], snB = snp[1];
        const int boffA = (kshA * 128 + quad * 16) ^ ((kshA & 7) << 4);
        const int boffB = boffA + 2048;             // (ksh+16)&7 == ksh&7

        // xn re-read per half-pass (dead after init: caps live regs)
        float4 xn0 = *(const float4*)(&xnormC[c * WT + wbase + quad * 4]);
        float4 xn1 = *(const float4*)(&xnormC[c * WT + wbase + 16 + quad * 4]);

        f32x4 a00, a01, a10, a11;                   // acc[mt][A/B]
        #pragma unroll
        for (int rg = 0; rg < 4; ++rg) {
          a00[rg] = xn0[rg] + snA;
          a01[rg] = xn0[rg] + snB;
          a10[rg] = xn1[rg] + snA;
          a11[rg] = xn1[rg] + snB;
        }

        // k-slice 0: two B frags, 4 independent MFMA
        {
          short8 bA0 = *(const short8*)(bsb + boffA);
          short8 bB0 = *(const short8*)(bsb + boffB);
          a00 = __builtin_amdgcn_mfma_f32_16x16x32_bf16(af[0][0], bA0, a00, 0, 0, 0);
          a01 = __builtin_amdgcn_mfma_f32_16x16x32_bf16(af[0][0], bB0, a01, 0, 0, 0);
          a10 = __builtin_amdgcn_mfma_f32_16x16x32_bf16(af[1][0], bA0, a10, 0, 0, 0);
          a11 = __builtin_amdgcn_mfma_f32_16x16x32_bf16(af[1][0], bB0, a11, 0, 0, 0);
        }
        // k-slice 1: two more B frags, 4 independent MFMA
        {
          short8 bA1 = *(const short8*)(bsb + (boffA ^ 64));  // swizzle-safe +64B
          short8 bB1 = *(const short8*)(bsb + (boffB ^ 64));
          a00 = __builtin_amdgcn_mfma_f32_16x16x32_bf16(af[0][1], bA1, a00, 0, 0, 0);
          a01 = __builtin_amdgcn_mfma_f32_16x16x32_bf16(af[0][1], bB1, a01, 0, 0, 0);
          a10 = __builtin_amdgcn_mfma_f32_16x16x32_bf16(af[1][1], bA1, a10, 0, 0, 0);
          a11 = __builtin_amdgcn_mfma_f32_16x16x32_bf16(af[1][1], bB1, a11, 0, 0, 0);
        }

        // 16 independent sqrts, then accumulate
        #pragma unroll
        for (int rg = 0; rg < 4; ++rg) {
          dist[0][pass * 4 + ntA][rg]     += __builtin_amdgcn_sqrtf(a00[rg]);
          dist[0][pass * 4 + ntA + 1][rg] += __builtin_amdgcn_sqrtf(a01[rg]);
          dist[1][pass * 4 + ntA][rg]     += __builtin_amdgcn_sqrtf(a10[rg]);
          dist[1][pass * 4 + ntA + 1][rg] += __builtin_amdgcn_sqrtf(a11[rg]);
        }
      }

      if (pass == 0) {
        // barrier 1: publishes Bs[1] (DMA issued a full phase ago); Bs[0] now dead
        __syncthreads();
        // ============ phase 1: compute K-half 1, DMA next c's K-half 0 ============
        if (c + 1 < Cn) {
          stage_half(0, c + 1, 0);
          load_x(c + 1);            // issued here: one pass to land before write_x
        }
      }
    }

    // late half of async-STAGE: convert + write next x tile into other buffer
    if (c + 1 < Cn) write_x(xbuf ^ 1);
    __syncthreads();  // barrier 2: publishes Xr writes + drains next-c DMA
  }

  // ---- min over windows, then global combine ----
  const int wql = w0 + wbase + quad * 4;
  #pragma unroll
  for (int nt2 = 0; nt2 < 8; ++nt2) {
    float v = 3.4e38f;
    #pragma unroll
    for (int mt = 0; mt < 2; ++mt)
      #pragma unroll
      for (int rg = 0; rg < 4; ++rg) {
        int wg = wql + mt * 16 + rg;
        float d = (wg < Wn) ? dist[mt][nt2][rg] : 3.4e38f;
        v = fminf(v, d);
      }
    v = fminf(v, __shfl_xor(v, 16, 64));
    v = fminf(v, __shfl_xor(v, 32, 64));
    if (lane < 16)
      atomicMin(&out[b * Kn + nt2 * 16 + n16], __float_as_uint(v));
  }
}

extern "C" void kernel_launch(void* const* d_in, const int* in_sizes, int n_in,
                              void* d_out, int out_size, void* d_ws, size_t ws_size,
                              hipStream_t stream) {
  const float* x  = (const float*)d_in[0];
  const float* sh = (const float*)d_in[1];
  unsigned int* out = (unsigned int*)d_out;
  unsigned short* hbf = (unsigned short*)d_ws;                      // 128 KB
  float* snorm = (float*)((char*)d_ws + (size_t)Cn * Kn * Sn * 2);  // +4 KB
  hipLaunchKernelGGL(prep_kernel, dim3(16), dim3(256), 0, stream, sh, out, hbf, snorm);
  hipLaunchKernelGGL(med_kernel, dim3(NWT, Bn), dim3(BDIM), 0, stream, x, hbf, snorm, out);
}

// Round 18
// 106.327 us; speedup vs baseline: 1.0671x; 1.0080x over previous
//
#include <hip/hip_runtime.h>

// MinEuclideanDistBlock: x(32,8,4096) f32, shapelets(8,128,64) f32 -> out(32,1,128) f32
// out[b,k] = min_w sum_c sqrt( xnorm[b,c,w] + snorm[c,k] - 2*sum_s x[b,c,w+s]*h[c,k,s] )
//
// FINAL (R20 = R17, the session-best verified kernel: med 52.2us, total 106us).
// R19's two tweaks (snT transpose, load_x move) measured neutral-to-negative
// (52.9us, bank conflicts +50%) -> reverted. Session floor analysis:
//  - Pipe floors: MFMA 6.8us, VALU ~11us (132M quarter-rate sqrts), LDS ~16-21us,
//    HBM ~1us. Measured 52us = 2.4x the largest -> cross-pipe dependency latency
//    at 3 waves/SIMD is the binding constraint.
//  - Levers closed empirically: ILP +4% (R16), TLP +4% (R17; 4 waves/SIMD needs
//    <=64 VGPR < dist's 64 alone), barrier removal -60% (R15), staging removal
//    -35% (R18: staging FILLS stall), big-WG occupancy null/spill (R9-R12),
//    K-splits negative (R7/R13/R14), vmcnt micro-moves null (R19).
//  - Past this: ground-up 8-phase counted-vmcnt pipeline (HK T3/T4), ~30-35us est,
//    race-prone -> out of scope for a polish pass.
//
// Structure: prep pre-converts shapelets to bf16(-2h) byte-swizzled ^((k&7)<<4) +
// snorm; med uses pass-granular Bs ping-pong via linear global_load_lds width=16,
// async x-stage split (load early/write late), paired-nt inner loop (4 indep MFMA
// chains, 16 indep sqrts), __launch_bounds__(256,3) pinning the 85-VGPR budget
// (measured 84 -> 3 waves/SIMD, occ 24%).

typedef short short8 __attribute__((ext_vector_type(8)));
typedef float f32x4 __attribute__((ext_vector_type(4)));

constexpr int Bn = 32, Cn = 8, Ln = 4096, Kn = 128, Sn = 64;
constexpr int Wn = Ln - Sn + 1;          // 4033
constexpr int WT = 128;                  // windows per block
constexpr int NWT = (Wn + WT - 1) / WT;  // 32
constexpr int BDIM = 256;

typedef const __attribute__((address_space(1))) unsigned int gas_u32;
typedef __attribute__((address_space(3))) unsigned int las_u32;

__device__ __forceinline__ unsigned int f2bf(float f) {
  unsigned int u = __float_as_uint(f);
  u += 0x7FFFu + ((u >> 16) & 1u);       // round-to-nearest-even
  return u >> 16;
}

// ws layout: [0, 128KB): ushort hbf[C][K][S] = bf16(-2*h), byte-swizzled ^((k&7)<<4)
//            [128KB, +4KB): float snorm[C][K]
__global__ void prep_kernel(const float* __restrict__ sh,
                            unsigned int* __restrict__ out,
                            unsigned short* __restrict__ hbf,
                            float* __restrict__ snorm) {
  int gid = blockIdx.x * blockDim.x + threadIdx.x;  // 0..4095
  out[gid] = 0x7F7FFFFFu;                           // FLT_MAX bits (Bn*Kn == 4096)
  if (gid < Cn * Kn) {
    const float4* row = (const float4*)(sh + (size_t)gid * Sn);
    char* rowb = (char*)hbf + (size_t)gid * (Sn * 2);   // 128B row
    const unsigned int sw = (gid & 7u) << 4;            // (k&7)<<4 byte swizzle
    float a = 0.f;
    #pragma unroll
    for (int i = 0; i < 16; ++i) {
      float4 v = row[i];
      a += v.x * v.x + v.y * v.y + v.z * v.z + v.w * v.w;
      unsigned int p0 = f2bf(-2.f * v.x) | (f2bf(-2.f * v.y) << 16);
      unsigned int p1 = f2bf(-2.f * v.z) | (f2bf(-2.f * v.w) << 16);
      *(uint2*)(rowb + ((8u * i) ^ sw)) = make_uint2(p0, p1);  // stays 8B-aligned
    }
    snorm[gid] = a;
  }
}

__launch_bounds__(BDIM, 3)
__global__ void med_kernel(const float* __restrict__ x,
                           const unsigned short* __restrict__ hbf,
                           const float* __restrict__ snorm,
                           unsigned int* __restrict__ out) {
  constexpr int XRS = 200;  // Xr row stride (elems); 400B, 16B-aligned rows
  __shared__ __align__(16) unsigned short Xr[2][8 * XRS];   // 2 x 3.2KB
  __shared__ __align__(16) unsigned short Bs[2][64 * Sn];   // 2 x 8KB (K-half each)
  __shared__ __align__(16) float xnormC[Cn * WT];           // 4KB
  __shared__ __align__(16) float snormC[Cn * Kn];           // 4KB

  const int tid  = threadIdx.x;
  const int b    = blockIdx.y;
  const int w0   = blockIdx.x * WT;
  const int lane = tid & 63;
  const int wv   = tid >> 6;     // wave 0..3
  const int quad = lane >> 4;    // 0..3
  const int n16  = lane & 15;
  const int wbase = wv * 32;     // this wave's window offset in tile

  const float* xb = x + (size_t)b * Cn * Ln;

  // ---- B staging: linear global->LDS DMA of one pre-swizzled 8KB K-half ----
  auto stage_half = [&](int bufi, int c, int p) {
    const char* src = (const char*)hbf + ((size_t)c * Kn + p * 64) * (Sn * 2);
    char* dst = (char*)&Bs[bufi][0];
    #pragma unroll
    for (int rep = 0; rep < 2; ++rep) {
      int q16 = (tid + rep * BDIM) * 16;   // lane-linear 16B chunks, 0..8191
      __builtin_amdgcn_global_load_lds((gas_u32*)(src + q16), (las_u32*)(dst + q16),
                                       16, 0, 0);
    }
  };

  // ---- X staging: LDS offsets hoisted; global idx recomputed (saves 3 VGPRs) ----
  int x_lds[3];
  #pragma unroll
  for (int rep = 0; rep < 3; ++rep) {
    int pid = tid + rep * BDIM;       // 0..767
    int r = pid / 96;
    int p = pid - r * 96;             // pair index 0..95 -> elems 2p,2p+1
    x_lds[rep] = r * XRS + 2 * p;
  }
  float xf[3][2];
  auto load_x = [&](int c) {
    const float* xc = xb + (size_t)c * Ln;
    #pragma unroll
    for (int rep = 0; rep < 3; ++rep) {
      int pid = tid + rep * BDIM;
      int r = pid / 96;
      int p = pid - r * 96;
      int i0 = w0 + r + 2 * p;
      xf[rep][0] = (i0 < Ln) ? xc[i0] : 0.f;
      xf[rep][1] = (i0 + 1 < Ln) ? xc[i0 + 1] : 0.f;
    }
  };
  auto write_x = [&](int bufi) {
    #pragma unroll
    for (int rep = 0; rep < 3; ++rep)
      *(unsigned int*)(&Xr[bufi][x_lds[rep]]) =
          f2bf(xf[rep][0]) | (f2bf(xf[rep][1]) << 16);
  };

  // snorm: one float4 per thread from prep output
  ((float4*)snormC)[tid] = ((const float4*)snorm)[tid];

  // ---- prologue: stage (c=0, pass=0) into Bs[0] (DMA overlaps xnorm compute) ----
  stage_half(0, 0, 0);
  load_x(0);

  // xnorm: 256 threads = 8c x 32 groups, 4 windows each (rolling update), fp32-exact
  {
    int c  = tid >> 5;
    int m0 = (tid & 31) * 4;
    const float* xc = xb + c * Ln;
    auto xq = [&](int i) -> float {
      float v = (i < Ln) ? xc[i] : 0.f;
      return v * v;
    };
    float s0 = 0.f;
    for (int s = 0; s < Sn; ++s) s0 += xq(w0 + m0 + s);
    float s1 = s0 - xq(w0 + m0 + 0) + xq(w0 + m0 + 64);
    float s2 = s1 - xq(w0 + m0 + 1) + xq(w0 + m0 + 65);
    float s3 = s2 - xq(w0 + m0 + 2) + xq(w0 + m0 + 66);
    xnormC[c * WT + m0 + 0] = s0;
    xnormC[c * WT + m0 + 1] = s1;
    xnormC[c * WT + m0 + 2] = s2;
    xnormC[c * WT + m0 + 3] = s3;
  }
  write_x(0);
  __syncthreads();  // drains prologue DMA (implicit vmcnt(0)) + covers norm writes

  float dist[2][8][4] = {};  // [mtile][ntile2][reg] summed distance over c

  for (int c = 0; c < Cn; ++c) {
    const int xbuf = c & 1;

    // ================= phase 0: compute K-half 0, DMA K-half 1 =================
    stage_half(1, c, 1);            // async DMA pass-1 half into Bs[1]
    if (c + 1 < Cn) load_x(c + 1);  // global loads into regs, waited at write_x

    // A fragments: lane m = n16, k = quad*8+j (+ks*32); one aligned b128 each
    short8 af[2][2];
    #pragma unroll
    for (int mt = 0; mt < 2; ++mt)
      #pragma unroll
      for (int ks = 0; ks < 2; ++ks) {
        int i = wbase + mt * 16 + n16 + ks * 32 + quad * 8;
        af[mt][ks] = *(const short8*)(&Xr[xbuf][(i & 7) * XRS + (i >> 3) * 8]);
      }

    #pragma unroll
    for (int pass = 0; pass < 2; ++pass) {
      const char* bsb = (const char*)&Bs[pass][0];
      // nt in PAIRS: 4 independent acc units, 8 MFMA grouped by k-slice,
      // 16 independent sqrts per half-pass.
      #pragma unroll
      for (int hp = 0; hp < 2; ++hp) {
        const int ntA = hp * 2, ntB = ntA + 1;
        const int kshA = ntA * 16 + n16;            // k-row within half: 0..63
        const float snA = snormC[c * Kn + pass * 64 + kshA];
        const float snB = snormC[c * Kn + pass * 64 + kshA + 16];
        const int boffA = (kshA * 128 + quad * 16) ^ ((kshA & 7) << 4);
        const int boffB = boffA + 2048;             // (ksh+16)&7 == ksh&7

        // xn re-read per half-pass (dead after init: caps live regs)
        float4 xn0 = *(const float4*)(&xnormC[c * WT + wbase + quad * 4]);
        float4 xn1 = *(const float4*)(&xnormC[c * WT + wbase + 16 + quad * 4]);

        f32x4 a00, a01, a10, a11;                   // acc[mt][A/B]
        #pragma unroll
        for (int rg = 0; rg < 4; ++rg) {
          a00[rg] = xn0[rg] + snA;
          a01[rg] = xn0[rg] + snB;
          a10[rg] = xn1[rg] + snA;
          a11[rg] = xn1[rg] + snB;
        }

        // k-slice 0: two B frags, 4 independent MFMA
        {
          short8 bA0 = *(const short8*)(bsb + boffA);
          short8 bB0 = *(const short8*)(bsb + boffB);
          a00 = __builtin_amdgcn_mfma_f32_16x16x32_bf16(af[0][0], bA0, a00, 0, 0, 0);
          a01 = __builtin_amdgcn_mfma_f32_16x16x32_bf16(af[0][0], bB0, a01, 0, 0, 0);
          a10 = __builtin_amdgcn_mfma_f32_16x16x32_bf16(af[1][0], bA0, a10, 0, 0, 0);
          a11 = __builtin_amdgcn_mfma_f32_16x16x32_bf16(af[1][0], bB0, a11, 0, 0, 0);
        }
        // k-slice 1: two more B frags, 4 independent MFMA
        {
          short8 bA1 = *(const short8*)(bsb + (boffA ^ 64));  // swizzle-safe +64B
          short8 bB1 = *(const short8*)(bsb + (boffB ^ 64));
          a00 = __builtin_amdgcn_mfma_f32_16x16x32_bf16(af[0][1], bA1, a00, 0, 0, 0);
          a01 = __builtin_amdgcn_mfma_f32_16x16x32_bf16(af[0][1], bB1, a01, 0, 0, 0);
          a10 = __builtin_amdgcn_mfma_f32_16x16x32_bf16(af[1][1], bA1, a10, 0, 0, 0);
          a11 = __builtin_amdgcn_mfma_f32_16x16x32_bf16(af[1][1], bB1, a11, 0, 0, 0);
        }

        // 16 independent sqrts, then accumulate
        #pragma unroll
        for (int rg = 0; rg < 4; ++rg) {
          dist[0][pass * 4 + ntA][rg] += __builtin_amdgcn_sqrtf(a00[rg]);
          dist[0][pass * 4 + ntB][rg] += __builtin_amdgcn_sqrtf(a01[rg]);
          dist[1][pass * 4 + ntA][rg] += __builtin_amdgcn_sqrtf(a10[rg]);
          dist[1][pass * 4 + ntB][rg] += __builtin_amdgcn_sqrtf(a11[rg]);
        }
      }

      if (pass == 0) {
        // barrier 1: publishes Bs[1] (DMA issued a full phase ago); Bs[0] now dead
        __syncthreads();
        // ============ phase 1: compute K-half 1, DMA next c's K-half 0 ============
        if (c + 1 < Cn) stage_half(0, c + 1, 0);
      }
    }

    // late half of async-STAGE: convert + write next x tile into other buffer
    if (c + 1 < Cn) write_x(xbuf ^ 1);
    __syncthreads();  // barrier 2: publishes Xr writes + drains next-c DMA
  }

  // ---- min over windows, then global combine ----
  const int wql = w0 + wbase + quad * 4;
  #pragma unroll
  for (int nt2 = 0; nt2 < 8; ++nt2) {
    float v = 3.4e38f;
    #pragma unroll
    for (int mt = 0; mt < 2; ++mt)
      #pragma unroll
      for (int rg = 0; rg < 4; ++rg) {
        int wg = wql + mt * 16 + rg;
        float d = (wg < Wn) ? dist[mt][nt2][rg] : 3.4e38f;
        v = fminf(v, d);
      }
    v = fminf(v, __shfl_xor(v, 16, 64));
    v = fminf(v, __shfl_xor(v, 32, 64));
    if (lane < 16)
      atomicMin(&out[b * Kn + nt2 * 16 + n16], __float_as_uint(v));
  }
}

extern "C" void kernel_launch(void* const* d_in, const int* in_sizes, int n_in,
                              void* d_out, int out_size, void* d_ws, size_t ws_size,
                              hipStream_t stream) {
  const float* x  = (const float*)d_in[0];
  const float* sh = (const float*)d_in[1];
  unsigned int* out = (unsigned int*)d_out;
  unsigned short* hbf = (unsigned short*)d_ws;                      // 128 KB
  float* snorm = (float*)((char*)d_ws + (size_t)Cn * Kn * Sn * 2);  // +4 KB
  hipLaunchKernelGGL(prep_kernel, dim3(16), dim3(256), 0, stream, sh, out, hbf, snorm);
  hipLaunchKernelGGL(med_kernel, dim3(NWT, Bn), dim3(BDIM), 0, stream, x, hbf, snorm, out);
}